// Round 1
// baseline (627.607 us; speedup 1.0000x reference)
//
#include <hip/hip_runtime.h>
#include <hip/hip_bf16.h>

#define D_MODEL 1024
#define N_HEAD  16
#define HD      64
#define T_SEQ   2048
#define B_SZ    4
#define M_ROWS  (B_SZ * T_SEQ)   // 8192

typedef __bf16 bf16;
typedef __bf16 bf16x4 __attribute__((ext_vector_type(4)));
typedef __bf16 bf16x8 __attribute__((ext_vector_type(8)));
typedef float  floatx4 __attribute__((ext_vector_type(4)));

#define LSTR 72   // padded LDS row stride (bf16 elems) for [*][64] tiles

__device__ inline floatx4 fzero4() {
    floatx4 z = {0.f, 0.f, 0.f, 0.f};
    return z;
}

// C[M=8192, N=1024] = A[8192,1024] @ W^T + bias.  W is [N,K] row-major (nn.Linear).
// AMODE: 0 = A fp32, 1 = A bf16.
// OMODE: 0 = write bf16 head-split [B,H,T,64]
//        1 = write bf16 head-split transposed [B,H,64,T]   (for V)
//        2 = write fp32 row-major [M,N] (final output)
template <int AMODE, int OMODE>
__global__ __launch_bounds__(256) void gemm_kernel(
    const void* __restrict__ Av, const float* __restrict__ W,
    const float* __restrict__ bias, void* __restrict__ Out)
{
    __shared__ bf16 ldsA[128 * LSTR];
    __shared__ bf16 ldsW[128 * LSTR];

    const int tid  = threadIdx.x;
    const int wave = tid >> 6, lane = tid & 63;
    const int quad = lane >> 4, l15 = lane & 15;
    const int wr = wave >> 1, wc = wave & 1;
    const int m0 = blockIdx.y * 128, n0 = blockIdx.x * 128;

    const float*  Af = (const float*)Av;
    const ushort* Ab = (const ushort*)Av;

    floatx4 acc[4][4];
#pragma unroll
    for (int i = 0; i < 4; ++i)
#pragma unroll
        for (int j = 0; j < 4; ++j) acc[i][j] = fzero4();

    for (int kt = 0; kt < 1024 / 64; ++kt) {
        // stage A tile [128][64] -> ldsA (bf16, stride LSTR)
#pragma unroll
        for (int i = 0; i < 8; ++i) {
            int chunk = i * 256 + tid;          // 0..2047
            int row   = chunk >> 4;             // 16 chunks per row
            int c4    = (chunk & 15) << 2;      // col base (x4)
            int gidx  = (m0 + row) * 1024 + kt * 64 + c4;
            bf16x4 bv;
            if (AMODE == 0) {
                const float4 v = *(const float4*)(Af + gidx);
                bv[0] = (bf16)v.x; bv[1] = (bf16)v.y;
                bv[2] = (bf16)v.z; bv[3] = (bf16)v.w;
            } else {
                bv = *(const bf16x4*)(Ab + gidx);
            }
            *(bf16x4*)(&ldsA[row * LSTR + c4]) = bv;
        }
        // stage W tile [128][64] -> ldsW
#pragma unroll
        for (int i = 0; i < 8; ++i) {
            int chunk = i * 256 + tid;
            int row   = chunk >> 4;
            int c4    = (chunk & 15) << 2;
            const float4 v = *(const float4*)(W + (n0 + row) * 1024 + kt * 64 + c4);
            bf16x4 bv;
            bv[0] = (bf16)v.x; bv[1] = (bf16)v.y;
            bv[2] = (bf16)v.z; bv[3] = (bf16)v.w;
            *(bf16x4*)(&ldsW[row * LSTR + c4]) = bv;
        }
        __syncthreads();
#pragma unroll
        for (int ks = 0; ks < 2; ++ks) {
            bf16x8 af[4], bw[4];
#pragma unroll
            for (int i = 0; i < 4; ++i)
                af[i] = *(const bf16x8*)(&ldsA[(wr * 64 + i * 16 + l15) * LSTR + ks * 32 + quad * 8]);
#pragma unroll
            for (int j = 0; j < 4; ++j)
                bw[j] = *(const bf16x8*)(&ldsW[(wc * 64 + j * 16 + l15) * LSTR + ks * 32 + quad * 8]);
#pragma unroll
            for (int i = 0; i < 4; ++i)
#pragma unroll
                for (int j = 0; j < 4; ++j)
                    acc[i][j] = __builtin_amdgcn_mfma_f32_16x16x32_bf16(af[i], bw[j], acc[i][j], 0, 0, 0);
        }
        __syncthreads();
    }

    // epilogue
#pragma unroll
    for (int i = 0; i < 4; ++i) {
#pragma unroll
        for (int j = 0; j < 4; ++j) {
#pragma unroll
            for (int r = 0; r < 4; ++r) {
                int m = m0 + wr * 64 + i * 16 + quad * 4 + r;
                int n = n0 + wc * 64 + j * 16 + l15;
                float val = acc[i][j][r] + bias[n];
                if (OMODE == 2) {
                    ((float*)Out)[(size_t)m * 1024 + n] = val;
                } else {
                    int b = m >> 11, t = m & 2047;
                    int h = n >> 6,  d = n & 63;
                    size_t addr;
                    if (OMODE == 0)
                        addr = ((size_t)(b * N_HEAD + h) * T_SEQ + t) * HD + d;
                    else
                        addr = ((size_t)(b * N_HEAD + h) * HD + d) * T_SEQ + t;
                    ((bf16*)Out)[addr] = (bf16)val;
                }
            }
        }
    }
}

// Flash-style causal attention.
// Qh, Kh: [B,H,T,64] bf16.  Vt: [B,H,64,T] bf16.  AO: [B,T, H*64] bf16.
// grid: (16 q-tiles, 64 bh), block 256 (4 waves x 32 q-rows).
__global__ __launch_bounds__(256) void attn_kernel(
    const bf16* __restrict__ Qh, const bf16* __restrict__ Kh,
    const bf16* __restrict__ Vt, bf16* __restrict__ AO)
{
    __shared__ char lds_raw[17408 + 34816];   // 52224 B
    bf16* Vts = (bf16*)lds_raw;               // [64][136]
    bf16* Ks  = (bf16*)(lds_raw + 17408);     // [128][72]
    bf16* Ps  = (bf16*)(lds_raw + 17408);     // [128][136] (aliases Ks; fits)
    bf16* Qs  = (bf16*)(lds_raw + 17408);     // [128][72] (staging only)

    const int tid  = threadIdx.x;
    const int wave = tid >> 6, lane = tid & 63;
    const int quad = lane >> 4, l15 = lane & 15;
    const int qt = blockIdx.x, bh = blockIdx.y;
    const size_t base = (size_t)bh * T_SEQ * HD;

    // stage Q tile [128][64] -> Qs
#pragma unroll
    for (int i = 0; i < 8; ++i) {
        int chunk = i * 256 + tid;
        int row = chunk >> 4, c4 = (chunk & 15) << 2;
        *(bf16x4*)(&Qs[row * 72 + c4]) =
            *(const bf16x4*)(Qh + base + (size_t)(qt * 128 + row) * HD + c4);
    }
    __syncthreads();
    bf16x8 qf[2][2];
#pragma unroll
    for (int ti = 0; ti < 2; ++ti)
#pragma unroll
        for (int ks = 0; ks < 2; ++ks)
            qf[ti][ks] = *(const bf16x8*)(&Qs[(wave * 32 + ti * 16 + l15) * 72 + ks * 32 + quad * 8]);

    const float scale2 = 0.125f * 1.44269504088896340736f;  // 1/sqrt(64) * log2(e)
    float mrow[2][4], lrow[2][4];
    floatx4 oacc[2][4];
#pragma unroll
    for (int ti = 0; ti < 2; ++ti) {
#pragma unroll
        for (int r = 0; r < 4; ++r) { mrow[ti][r] = -1e30f; lrow[ti][r] = 0.f; }
#pragma unroll
        for (int nj = 0; nj < 4; ++nj) oacc[ti][nj] = fzero4();
    }

    for (int kt = 0; kt <= qt; ++kt) {
        __syncthreads();   // previous P/V reads done; Q-region reusable
        // stage K tile [128][64] -> Ks
#pragma unroll
        for (int i = 0; i < 8; ++i) {
            int chunk = i * 256 + tid;
            int row = chunk >> 4, c4 = (chunk & 15) << 2;
            *(bf16x4*)(&Ks[row * 72 + c4]) =
                *(const bf16x4*)(Kh + base + (size_t)(kt * 128 + row) * HD + c4);
        }
        // stage V^T tile [64][128] -> Vts
#pragma unroll
        for (int i = 0; i < 8; ++i) {
            int chunk = i * 256 + tid;
            int d = chunk >> 5, k4 = (chunk & 31) << 2;
            *(bf16x4*)(&Vts[d * 136 + k4]) =
                *(const bf16x4*)(Vt + base + (size_t)d * T_SEQ + kt * 128 + k4);
        }
        __syncthreads();

        // S = Q K^T  (per wave: 32 q-rows x 128 k-cols)
        floatx4 sacc[2][8];
#pragma unroll
        for (int ti = 0; ti < 2; ++ti)
#pragma unroll
            for (int tj = 0; tj < 8; ++tj) sacc[ti][tj] = fzero4();
#pragma unroll
        for (int ks = 0; ks < 2; ++ks) {
#pragma unroll
            for (int tj = 0; tj < 8; ++tj) {
                bf16x8 kf = *(const bf16x8*)(&Ks[(tj * 16 + l15) * 72 + ks * 32 + quad * 8]);
                sacc[0][tj] = __builtin_amdgcn_mfma_f32_16x16x32_bf16(qf[0][ks], kf, sacc[0][tj], 0, 0, 0);
                sacc[1][tj] = __builtin_amdgcn_mfma_f32_16x16x32_bf16(qf[1][ks], kf, sacc[1][tj], 0, 0, 0);
            }
        }

        // online softmax; overwrite sacc with p = 2^(s' - m_new)
        const bool diag = (kt == qt);
#pragma unroll
        for (int ti = 0; ti < 2; ++ti) {
#pragma unroll
            for (int r = 0; r < 4; ++r) {
                int qrow = wave * 32 + ti * 16 + quad * 4 + r;   // local q row
                float sv[8];
                float mx = -1e30f;
#pragma unroll
                for (int tj = 0; tj < 8; ++tj) {
                    float s = sacc[ti][tj][r] * scale2;
                    if (diag && (tj * 16 + l15) > qrow) s = -1e30f;
                    sv[tj] = s;
                    mx = fmaxf(mx, s);
                }
#pragma unroll
                for (int off = 1; off < 16; off <<= 1)
                    mx = fmaxf(mx, __shfl_xor(mx, off));
                float mnew  = fmaxf(mrow[ti][r], mx);
                float alpha = exp2f(mrow[ti][r] - mnew);
                float rsum  = 0.f;
#pragma unroll
                for (int tj = 0; tj < 8; ++tj) {
                    float p = exp2f(sv[tj] - mnew);
                    sacc[ti][tj][r] = p;
                    rsum += p;
                }
#pragma unroll
                for (int off = 1; off < 16; off <<= 1)
                    rsum += __shfl_xor(rsum, off);
                lrow[ti][r] = lrow[ti][r] * alpha + rsum;
                mrow[ti][r] = mnew;
#pragma unroll
                for (int nj = 0; nj < 4; ++nj)
                    oacc[ti][nj][r] *= alpha;
            }
        }
        __syncthreads();   // all waves done reading Ks (P aliases it)

        // write P (bf16) to LDS in row-major [128][136]
#pragma unroll
        for (int ti = 0; ti < 2; ++ti)
#pragma unroll
            for (int tj = 0; tj < 8; ++tj)
#pragma unroll
                for (int r = 0; r < 4; ++r)
                    Ps[(wave * 32 + ti * 16 + quad * 4 + r) * 136 + tj * 16 + l15] =
                        (bf16)sacc[ti][tj][r];
        __syncthreads();

        // O += P V
#pragma unroll
        for (int ks = 0; ks < 4; ++ks) {
            bf16x8 pf[2];
            pf[0] = *(const bf16x8*)(&Ps[(wave * 32 + 0 * 16 + l15) * 136 + ks * 32 + quad * 8]);
            pf[1] = *(const bf16x8*)(&Ps[(wave * 32 + 1 * 16 + l15) * 136 + ks * 32 + quad * 8]);
#pragma unroll
            for (int nj = 0; nj < 4; ++nj) {
                bf16x8 vf = *(const bf16x8*)(&Vts[(nj * 16 + l15) * 136 + ks * 32 + quad * 8]);
                oacc[0][nj] = __builtin_amdgcn_mfma_f32_16x16x32_bf16(pf[0], vf, oacc[0][nj], 0, 0, 0);
                oacc[1][nj] = __builtin_amdgcn_mfma_f32_16x16x32_bf16(pf[1], vf, oacc[1][nj], 0, 0, 0);
            }
        }
    }

    // epilogue: O /= l, store to AO [B,T,D]
    const int b = bh >> 4, h = bh & 15;
#pragma unroll
    for (int ti = 0; ti < 2; ++ti) {
#pragma unroll
        for (int r = 0; r < 4; ++r) {
            float rl = 1.f / lrow[ti][r];
            int qrow = qt * 128 + wave * 32 + ti * 16 + quad * 4 + r;
#pragma unroll
            for (int nj = 0; nj < 4; ++nj) {
                int d = nj * 16 + l15;
                AO[((size_t)(b * T_SEQ + qrow)) * D_MODEL + h * HD + d] =
                    (bf16)(oacc[ti][nj][r] * rl);
            }
        }
    }
}

extern "C" void kernel_launch(void* const* d_in, const int* in_sizes, int n_in,
                              void* d_out, int out_size, void* d_ws, size_t ws_size,
                              hipStream_t stream)
{
    const float* q  = (const float*)d_in[0];
    const float* k  = (const float*)d_in[1];
    const float* v  = (const float*)d_in[2];
    const float* wq = (const float*)d_in[3];
    const float* bq = (const float*)d_in[4];
    const float* wk = (const float*)d_in[5];
    const float* bk = (const float*)d_in[6];
    const float* wv = (const float*)d_in[7];
    const float* bv = (const float*)d_in[8];
    const float* wo = (const float*)d_in[9];
    const float* bo = (const float*)d_in[10];

    char* ws = (char*)d_ws;
    const size_t SZ = (size_t)M_ROWS * D_MODEL * sizeof(bf16);  // 16 MiB
    bf16* Qh = (bf16*)(ws);
    bf16* Kh = (bf16*)(ws + SZ);
    bf16* Vt = (bf16*)(ws + 2 * SZ);
    bf16* AO = (bf16*)(ws + 3 * SZ);

    dim3 gg(8, 64), gb(256);
    hipLaunchKernelGGL((gemm_kernel<0, 0>), gg, gb, 0, stream, (const void*)q, wq, bq, (void*)Qh);
    hipLaunchKernelGGL((gemm_kernel<0, 0>), gg, gb, 0, stream, (const void*)k, wk, bk, (void*)Kh);
    hipLaunchKernelGGL((gemm_kernel<0, 1>), gg, gb, 0, stream, (const void*)v, wv, bv, (void*)Vt);
    hipLaunchKernelGGL(attn_kernel, dim3(16, 64), gb, 0, stream, Qh, Kh, Vt, AO);
    hipLaunchKernelGGL((gemm_kernel<1, 2>), gg, gb, 0, stream, (const void*)AO, wo, bo, d_out);
}